// Round 12
// baseline (125.509 us; speedup 1.0000x reference)
//
#include <hip/hip_runtime.h>
#include <stdint.h>

typedef __bf16 bf16x8 __attribute__((ext_vector_type(8)));
typedef float floatx4 __attribute__((ext_vector_type(4)));
typedef float floatx4u __attribute__((ext_vector_type(4), aligned(4)));
typedef unsigned int u32x4 __attribute__((ext_vector_type(4)));
typedef unsigned short u16;
typedef unsigned int u32;

#define CIN   64
#define COUT  128
#define H_    1855
#define KNB   6
#define KTOT  448      // (1+KNB)*CIN
#define NSTEPS 14      // KTOT / 32

// xt3 pitch = 8192 (REVERTED from R11's 8448): at 8192 k_main's concurrent
// gathers are perfectly channel-partitioned by bp (colOff = bp*256+... =
// distinct low bits per co-resident block); R11 proved randomizing this
// costs ~11 µs. k_prep's write camping is fixed by GRID AXIS SWAP instead.
#define XPITCH2 4096   // pitch in u16

// Half-buffer geometry (R3-verified): half-tile = 16 hl rows x 4 s-slots.
// Row = 4*256+16 pad = 1040 B. 4 rotating half-buffers.
#define HROW   1040
#define HBUFSZ 16640   // 16 * HROW

// ws layout (bytes)
#define WP_OFF     ((size_t)H_ * 8192)                     // xt3: bf16 [h][4096]
#define CINV_OFF   (WP_OFF + (size_t)COUT * KTOT * 2)
#define ZERO_OFF   (CINV_OFF + 7424)                       // 512-B zero page (256-B aligned)
#define SRCOFF_OFF (ZERO_OFF + 1024)                       // u32 [H][8] gather row offsets
#define INVOFF 0xFFFFFFFFu

#define PIN4(v) asm volatile("" : "+v"(v))

typedef __attribute__((address_space(1))) unsigned int as1_u32;
typedef __attribute__((address_space(3))) unsigned int as3_u32;
static __device__ __forceinline__ void ld16_to_lds(const void* g, void* l) {
    __builtin_amdgcn_global_load_lds((const as1_u32*)g, (as3_u32*)l, 16, 0, 0);
}

static __device__ inline u16 f32_to_bf16(float f) {
    u32 u = __float_as_uint(f);
    u32 r = (u + 0x7FFFu + ((u >> 16) & 1u)) >> 16;
    return (u16)r;
}

// ---- K1 (fused): transpose x f32 [bc][h] -> xt3 bf16 [h][bc], plus
// weight-pack / inverse-counts / zero-page / gather-offset table.
// GRID = (65, 29): blockIdx.x = bc-tile (FAST-VARYING -> concurrent blocks
// write distinct bc0 -> distinct channel slots, killing the write camping
// that R11's pitch change exposed); blockIdx.y = h-tile. x==64 = pack stripe.
__global__ __launch_bounds__(256) void k_prep(const float* __restrict__ x,
                                              const float* __restrict__ wc,
                                              const float* __restrict__ wn,
                                              const int* __restrict__ nbr,
                                              u16* __restrict__ xt3,
                                              u16* __restrict__ wp,
                                              float* __restrict__ cInvG,
                                              u32* __restrict__ zeroPg,
                                              u32* __restrict__ srcOff) {
    int tid = threadIdx.x;
    if (blockIdx.x == 64) {            // ---- pack stripe (29 blocks, strided)
        for (int tg = blockIdx.y * 256 + tid; tg < COUT * KTOT; tg += 29 * 256) {
            if (tg < 128) zeroPg[tg] = 0u;           // 512-B zero page
            if (tg < H_) {
                int cnt = 1;
#pragma unroll
                for (int j = 0; j < KNB; ++j) cnt += (nbr[tg * KNB + j] >= 0) ? 1 : 0;
                cInvG[tg] = 1.0f / (float)cnt;
            }
            if (tg < H_ * 8) {
                int h = tg >> 3, s = tg & 7;
                u32 e;
                if (s == 0) e = (u32)h * 8192u;
                else if (s <= 6) {
                    int n = nbr[h * KNB + (s - 1)];
                    e = (n >= 0) ? (u32)n * 8192u : INVOFF;
                } else e = INVOFF;
                srcOff[tg] = e;
            }
            int o = tg / KTOT;
            int rem = tg - o * KTOT;
            int s = rem >> 6, c = rem & 63;
            float v = (s == 0) ? wc[o * CIN + c]
                               : wn[(o * CIN + c) * KNB + (s - 1)];
            wp[tg] = f32_to_bf16(v);
        }
        return;
    }
    // ---- transpose stripe: tile = u32 (bc even|odd packed), stride 34
    __shared__ u32 t32[64][34];
    int h0  = blockIdx.y * 64;
    int bc0 = blockIdx.x * 64;
    int lh = tid & 15;                 // h-quad (4 h per thread)
    int rq = tid >> 4;                 // 0..15 rowpair sub-index
    bool safe = (h0 + 64 <= H_);
#pragma unroll
    for (int it = 0; it < 2; ++it) {
        int rp = it * 16 + rq;         // rowpair 0..31 -> rows 2rp, 2rp+1
        size_t r0 = (size_t)(bc0 + rp * 2) * H_;
        size_t r1 = r0 + H_;
        int h = h0 + lh * 4;
        u32 p[4];
        if (safe) {
            floatx4u f0 = *(const floatx4u*)(x + r0 + h);
            floatx4u f1 = *(const floatx4u*)(x + r1 + h);
#pragma unroll
            for (int j = 0; j < 4; ++j)
                p[j] = (u32)f32_to_bf16(f0[j]) | ((u32)f32_to_bf16(f1[j]) << 16);
        } else {
#pragma unroll
            for (int j = 0; j < 4; ++j) {
                int hh = h + j;
                u16 a = 0, b = 0;
                if (hh < H_) { a = f32_to_bf16(x[r0 + hh]); b = f32_to_bf16(x[r1 + hh]); }
                p[j] = (u32)a | ((u32)b << 16);
            }
        }
#pragma unroll
        for (int j = 0; j < 4; ++j) t32[lh * 4 + j][rp] = p[j];
    }
    __syncthreads();
    int bg = tid & 7;                  // bc-octet
    int hb = tid >> 3;                 // 0..31
#pragma unroll
    for (int ii = 0; ii < 2; ++ii) {
        int hl = ii * 32 + hb;
        int hh = h0 + hl;
        uint2 qa = *(const uint2*)&t32[hl][bg * 4];
        uint2 qb = *(const uint2*)&t32[hl][bg * 4 + 2];
        u32x4 q = {qa.x, qa.y, qb.x, qb.y};
        if (hh < H_)
            *(u32x4*)(xt3 + (size_t)hh * XPITCH2 + bc0 + bg * 8) = q;
    }
}

// ---- K3: PERSISTENT gather-GEMM (R8-verified, best-known: ~43 µs) ---------
// grid = 512 = 32 bp x 16 slots — 2 blocks/CU, all co-resident, XCD = bp&7
// pinned for block lifetime (bp slice L2-hot + conflict-free channel
// partition by bp at pitch 8192). Slot j -> hs = j, j+16.
// Depth-3 / 4-buffer / counted-vmcnt ladder verbatim.
__global__ __launch_bounds__(256, 2) void k_main(const u16* __restrict__ xt3,
                                                 const u16* __restrict__ wp,
                                                 const float* __restrict__ bias,
                                                 const float* __restrict__ cInvG,
                                                 const u32* __restrict__ srcOff,
                                                 float* __restrict__ out) {
    __shared__ __align__(16) char LDS[4 * HBUFSZ];

    int tid  = threadIdx.x;
    int gbl  = blockIdx.x;
    int bp   = gbl & 31;          // b-pair, FIXED for block lifetime; XCD = bp&7
    int slot = gbl >> 5;          // 0..15
    int b0   = bp * 2;

    int lane = tid & 63;
    int wave = tid >> 6;          // 0..3
    int col  = lane & 15;
    int quad = lane >> 4;
    int m0w  = wave * 32;
    int lane16 = lane & 15;
    int ssub = lane >> 4;
    int bl   = lane16 >> 3;
    int chunk = lane16 & 7;

    const char* xb = (const char*)xt3;   // == d_ws base; all offsets relative

    // A fragments (weights): A[m=col][k=quad*8+j]; 112 regs, pinned.
    u32x4 afrag[2][NSTEPS];
#pragma unroll
    for (int mt = 0; mt < 2; ++mt) {
        int o = m0w + mt * 16 + col;
#pragma unroll
        for (int kk = 0; kk < NSTEPS; ++kk)
            afrag[mt][kk] = *(const u32x4*)(wp + o * KTOT + kk * 32 + quad * 8);
    }
#pragma unroll
    for (int mt = 0; mt < 2; ++mt)
#pragma unroll
        for (int kk = 0; kk < NSTEPS; ++kk)
            PIN4(afrag[mt][kk]);

    float biasv[2][4];
#pragma unroll
    for (int mt = 0; mt < 2; ++mt)
#pragma unroll
        for (int r = 0; r < 4; ++r)
            biasv[mt][r] = bias[m0w + mt * 16 + quad * 4 + r];

    u32 colOff = (u32)((b0 + bl) * 128 + chunk * 16);
    u32 zOff   = (u32)ZERO_OFF + (u32)(lane16 * 16);

    int rb0 = col * HROW + quad * 16;
    int rb1 = rb0 + 128;
    char* bufA0 = LDS;
    char* bufA1 = LDS + HBUFSZ;
    char* bufA2 = LDS + 2 * HBUFSZ;
    char* bufA3 = LDS + 3 * HBUFSZ;

#define SGH(t, sg, bufp) do {                                                 \
    char* _d = (bufp) + (wave * 4) * HROW;                                    \
    _Pragma("unroll")                                                         \
    for (int _i = 0; _i < 4; ++_i)                                            \
        ld16_to_lds(xb + offs[t][sg][_i], _d + _i * HROW);                    \
} while (0)

#define CA(accv, bufp) do {  /* k-steps 0..7, zero-init */                    \
    _Pragma("unroll") for (int _m = 0; _m < 2; ++_m)                          \
    _Pragma("unroll") for (int _n = 0; _n < 2; ++_n)                          \
        accv[_m][_n] = (floatx4){0.0f, 0.0f, 0.0f, 0.0f};                     \
    __builtin_amdgcn_s_setprio(1);                                            \
    _Pragma("unroll")                                                         \
    for (int kk = 0; kk < 8; ++kk) {                                          \
        int koff = (kk >> 1) * 256 + (kk & 1) * 64;                           \
        bf16x8 bfa = *(const bf16x8*)((bufp) + rb0 + koff);                   \
        bf16x8 bfb = *(const bf16x8*)((bufp) + rb1 + koff);                   \
        bf16x8 a0 = __builtin_bit_cast(bf16x8, afrag[0][kk]);                 \
        bf16x8 a1 = __builtin_bit_cast(bf16x8, afrag[1][kk]);                 \
        accv[0][0] = __builtin_amdgcn_mfma_f32_16x16x32_bf16(a0, bfa, accv[0][0], 0, 0, 0); \
        accv[1][0] = __builtin_amdgcn_mfma_f32_16x16x32_bf16(a1, bfa, accv[1][0], 0, 0, 0); \
        accv[0][1] = __builtin_amdgcn_mfma_f32_16x16x32_bf16(a0, bfb, accv[0][1], 0, 0, 0); \
        accv[1][1] = __builtin_amdgcn_mfma_f32_16x16x32_bf16(a1, bfb, accv[1][1], 0, 0, 0); \
    }                                                                         \
    __builtin_amdgcn_s_setprio(0);                                            \
} while (0)

#define CB(accv, bufp) do {  /* k-steps 8..13, accumulate */                  \
    __builtin_amdgcn_s_setprio(1);                                            \
    _Pragma("unroll")                                                         \
    for (int kk = 8; kk < 14; ++kk) {                                         \
        int koff = ((kk - 8) >> 1) * 256 + (kk & 1) * 64;                     \
        bf16x8 bfa = *(const bf16x8*)((bufp) + rb0 + koff);                   \
        bf16x8 bfb = *(const bf16x8*)((bufp) + rb1 + koff);                   \
        bf16x8 a0 = __builtin_bit_cast(bf16x8, afrag[0][kk]);                 \
        bf16x8 a1 = __builtin_bit_cast(bf16x8, afrag[1][kk]);                 \
        accv[0][0] = __builtin_amdgcn_mfma_f32_16x16x32_bf16(a0, bfa, accv[0][0], 0, 0, 0); \
        accv[1][0] = __builtin_amdgcn_mfma_f32_16x16x32_bf16(a1, bfa, accv[1][0], 0, 0, 0); \
        accv[0][1] = __builtin_amdgcn_mfma_f32_16x16x32_bf16(a0, bfb, accv[0][1], 0, 0, 0); \
        accv[1][1] = __builtin_amdgcn_mfma_f32_16x16x32_bf16(a1, bfb, accv[1][1], 0, 0, 0); \
    }                                                                         \
    __builtin_amdgcn_s_setprio(0);                                            \
} while (0)

// Pair epilogue via wave-private E overlay in a freed half-buffer: writes
// XOR-swizzled by (o&7), conflict-free b128 readback, 8 float4 stores/lane
// (128-B segments). BND (final epilogue of final hs only) masks the ragged
// float — uncounted position, ladder counts stay exact.
#define EPI(pp, a0v, a1v, Ebuf, BND) do {                                     \
    float* _E = (float*)((Ebuf) + (wave * 4) * HROW);                         \
    int _o8 = lane >> 3, _h4 = lane & 7;                                      \
    _Pragma("unroll")                                                         \
    for (int _nt = 0; _nt < 2; ++_nt) {                                       \
        asm volatile("s_waitcnt lgkmcnt(0)" ::: "memory");                    \
        _Pragma("unroll") for (int _mt = 0; _mt < 2; ++_mt)                   \
        _Pragma("unroll") for (int _r = 0; _r < 4; ++_r) {                    \
            int _ol = _mt * 16 + quad * 4 + _r;                               \
            int _x0 = ((col >> 2) ^ (_ol & 7));                               \
            int _x1 = (((16 + col) >> 2) ^ (_ol & 7));                        \
            _E[_ol * 32 + (_x0 << 2) + (col & 3)] =                           \
                a0v[_mt][_nt][_r] * icv[(pp) * 2]     + biasv[_mt][_r];       \
            _E[_ol * 32 + (_x1 << 2) + (col & 3)] =                           \
                a1v[_mt][_nt][_r] * icv[(pp) * 2 + 1] + biasv[_mt][_r];       \
        }                                                                     \
        asm volatile("s_waitcnt lgkmcnt(0)" ::: "memory");                    \
        _Pragma("unroll")                                                     \
        for (int _q = 0; _q < 4; ++_q) {                                      \
            int _ol = _q * 8 + _o8;                                           \
            floatx4 _v = *(const floatx4*)(_E + _ol * 32 + ((_h4 ^ (_ol & 7)) << 2)); \
            int _hh = h0 + (pp) * 32 + _h4 * 4;                               \
            float* _dst = out + (size_t)(b0 + _nt) * ((size_t)COUT * H_)      \
                        + (size_t)(m0w + _ol) * H_ + _hh;                     \
            if (!(BND)) {                                                     \
                *(floatx4u*)_dst = _v;                                        \
            } else {                                                          \
                _Pragma("unroll") for (int _e = 0; _e < 4; ++_e)              \
                    if (_hh + _e < H_) _dst[_e] = _v[_e];                     \
            }                                                                 \
        }                                                                     \
    }                                                                         \
} while (0)

#define VW(n)  asm volatile("s_waitcnt vmcnt(" #n ") lgkmcnt(0)" ::: "memory")
#define BAR()  __builtin_amdgcn_s_barrier()

    floatx4 acc0[2][2], acc1[2][2];
    int nhs = (slot + 16 <= 28) ? 2 : 1;

    for (int q = 0; q < nhs; ++q) {
        int hs = slot + q * 16;       // 0..28
        int h0 = hs * 64;
        bool bnd = (hs == 28);

        float icv[4];
#pragma unroll
        for (int t = 0; t < 4; ++t) {
            int hic = h0 + t * 16 + col;
            icv[t] = cInvG[hic < H_ ? hic : 0];
        }
        u32 offs[4][2][4];
#pragma unroll
        for (int t = 0; t < 4; ++t)
#pragma unroll
            for (int sg = 0; sg < 2; ++sg)
#pragma unroll
                for (int i = 0; i < 4; ++i) {
                    int hh = h0 + t * 16 + wave * 4 + i;
                    int s  = sg * 4 + ssub;
                    u32 e = (hh < H_) ? srcOff[hh * 8 + s] : INVOFF;
                    offs[t][sg][i] = (e == INVOFF) ? zOff : (e + colOff);
                }

        // ---- R3-verified ladder (verbatim) ----
        SGH(0, 0, bufA0);                 // S0
        SGH(0, 1, bufA1);                 // S1
        SGH(1, 0, bufA2);                 // S2

        VW(8);  BAR(); SGH(1, 1, bufA3);  CA(acc0, bufA0);   // ph0
        VW(8);  BAR(); SGH(2, 0, bufA0);  CB(acc0, bufA1);   // ph1
        VW(8);  BAR(); SGH(2, 1, bufA1);  CA(acc1, bufA2);   // ph2
        VW(8);  BAR();                    CB(acc1, bufA3);   // ph3
        EPI(0, acc0, acc1, bufA2, false);
        VW(12); BAR(); SGH(3, 0, bufA2);  CA(acc0, bufA0);   // ph4
        VW(12); BAR(); SGH(3, 1, bufA3);  CB(acc0, bufA1);   // ph5
        VW(4);  BAR();                    CA(acc1, bufA2);   // ph6
        VW(0);  BAR();                    CB(acc1, bufA3);   // ph7
        EPI(1, acc0, acc1, bufA2, bnd);

        if (q + 1 < nhs) { VW(0); BAR(); }
    }

#undef SGH
#undef CA
#undef CB
#undef EPI
#undef VW
#undef BAR
}

extern "C" void kernel_launch(void* const* d_in, const int* in_sizes, int n_in,
                              void* d_out, int out_size, void* d_ws, size_t ws_size,
                              hipStream_t stream) {
    const float* x    = (const float*)d_in[0];   // f32 [64,64,1855]
    const int*   nbr  = (const int*)d_in[1];     // int32 [1855,6]
    const float* wc   = (const float*)d_in[2];   // f32 [128,64]
    const float* wn   = (const float*)d_in[3];   // f32 [128,64,6]
    const float* bias = (const float*)d_in[4];   // f32 [128]

    u16*   xt3    = (u16*)d_ws;
    u16*   wp     = (u16*)((char*)d_ws + WP_OFF);
    float* cInvG  = (float*)((char*)d_ws + CINV_OFF);
    u32*   zeroPg = (u32*)((char*)d_ws + ZERO_OFF);
    u32*   srcOff = (u32*)((char*)d_ws + SRCOFF_OFF);

    k_prep<<<dim3(65, 29), dim3(256), 0, stream>>>(
        x, wc, wn, nbr, xt3, wp, cInvG, zeroPg, srcOff);
    k_main<<<dim3(512), dim3(256), 0, stream>>>(
        xt3, wp, bias, cInvG, srcOff, (float*)d_out);
}